// Round 2
// baseline (1823.345 us; speedup 1.0000x reference)
//
#include <hip/hip_runtime.h>
#include <hip/hip_bf16.h>
#include <stdint.h>

// LSTM: B=65536, T=28, IN=28, H=128. Final hidden [B,H] output.
// Fused single kernel: block = 32 batch rows x all 28 timesteps.
// 4 waves/block, wave w owns gate w (0=f,1=i,2=n,3=o): 128 outputs/wave,
// weights held as MFMA B-fragments in registers (persist across steps).
// h: LDS round trip (C-layout -> A-layout). Gates: bf16 LDS exchange buffer.
// Dtype self-detection: detect_dtype scans W_f bit patterns -> flag in d_ws;
// both fp32/bf16 template variants launch, wrong one returns immediately.

#define T_STEPS   28
#define HDIM      128
#define KIN       156            // H + IN
#define MB        32             // batch rows per block
#define NTILES    8              // 128 gate outputs / 16
#define KSTEPS    5              // K=160: 4x32 (h) + 1x32 (x: 28 real + 4 pad)
#define HLDS_ST   136            // h_lds row stride in shorts (128 + 8 pad)
#define XLDS_ST   40             // x_lds row stride in shorts (32 + 8 pad)
#define GB_MP     36             // gbuf inner (m) stride in shorts (32 + 4 pad)

typedef __attribute__((ext_vector_type(8))) short  short8;
typedef __attribute__((ext_vector_type(4))) float  floatx4;

union Frag { short8 f; uint2 u2[2]; unsigned short s[8]; };
union Pk4  { uint2 u2; unsigned short s[4]; };

__device__ __forceinline__ float bf2f(unsigned short v) {
    union { uint32_t u; float f; } c; c.u = ((uint32_t)v) << 16; return c.f;
}
__device__ __forceinline__ unsigned short f2bf(float x) {
    union { float f; uint32_t u; } c; c.f = x;          // RNE bf16 (finite inputs)
    return (unsigned short)((c.u + 0x7FFFu + ((c.u >> 16) & 1u)) >> 16);
}
// NaN-free: x->+inf gives 1-2/inf = 1; x->-inf gives 1-2/1... e=0 -> 1-2 = -1.
__device__ __forceinline__ float sigm(float x) { return 1.0f / (1.0f + __expf(-x)); }
__device__ __forceinline__ float tanh_f(float x) {
    float e = __expf(2.0f * x);
    return 1.0f - 2.0f / (e + 1.0f);
}

// bf16 |W_f| <= 0.08 -> exponent field <= 123 always. fp32 read as shorts:
// mantissa halves are ~uniform -> exponent field >= 127 with p~0.5/short.
__global__ void detect_dtype(const unsigned short* __restrict__ wf, int* __restrict__ flag) {
    const int lane = threadIdx.x;
    bool big = false;
    #pragma unroll
    for (int i = 0; i < 4; ++i) {
        unsigned e = (wf[lane * 4 + i] >> 7) & 0xFFu;
        if (e >= 127u) big = true;
    }
    const int isfp32 = __any(big) ? 1 : 0;
    if (lane == 0) *flag = isfp32;
}

template <bool FP32>
__global__ __launch_bounds__(256, 1)
void lstm_fused(const void* __restrict__ x_,
                const void* __restrict__ Wf_, const void* __restrict__ bf_,
                const void* __restrict__ Wi_, const void* __restrict__ bi_,
                const void* __restrict__ Wc_, const void* __restrict__ bc_,
                const void* __restrict__ Wo_, const void* __restrict__ bo_,
                void* __restrict__ out_, const int* __restrict__ flag)
{
    if (*flag != (FP32 ? 1 : 0)) return;   // wrong-dtype variant: uniform exit

    __shared__ __align__(16) unsigned short h_lds[MB * HLDS_ST];       // 8704 B
    __shared__ __align__(16) unsigned short x_lds[2 * MB * XLDS_ST];   // 5120 B
    __shared__ __align__(16) unsigned short gbuf[4 * HDIM * GB_MP];    // 36864 B

    const int tid  = threadIdx.x;
    const int wave = tid >> 6;
    const int lane = tid & 63;
    const int q    = lane >> 4;    // quad
    const int cc   = lane & 15;
    const int b0   = blockIdx.x * MB;

    const void* Wg_ = (wave == 0) ? Wf_ : (wave == 1) ? Wi_ : (wave == 2) ? Wc_ : Wo_;
    const void* bg_ = (wave == 0) ? bf_ : (wave == 1) ? bi_ : (wave == 2) ? bc_ : bo_;

    // ---- persistent weight B-fragments: lane holds W[n=nt*16+cc][k=ks*32+q*8..+7]
    Frag  bfr[NTILES][KSTEPS];
    float bias_r[NTILES];
    #pragma unroll
    for (int nt = 0; nt < NTILES; ++nt) {
        const int n = nt * 16 + cc;
        if constexpr (FP32) bias_r[nt] = ((const float*)bg_)[n];
        else                bias_r[nt] = bf2f(((const unsigned short*)bg_)[n]);
        #pragma unroll
        for (int ks = 0; ks < KSTEPS; ++ks) {
            const int k0 = ks * 32 + q * 8;
            Frag fr;
            if constexpr (FP32) {
                const float* p = (const float*)Wg_ + n * KIN + k0;
                float4 lo = *(const float4*)p;
                fr.s[0] = f2bf(lo.x); fr.s[1] = f2bf(lo.y);
                fr.s[2] = f2bf(lo.z); fr.s[3] = f2bf(lo.w);
                if (ks < 4 || q < 3) {
                    float4 hi = *(const float4*)(p + 4);
                    fr.s[4] = f2bf(hi.x); fr.s[5] = f2bf(hi.y);
                    fr.s[6] = f2bf(hi.z); fr.s[7] = f2bf(hi.w);
                } else {
                    fr.s[4] = fr.s[5] = fr.s[6] = fr.s[7] = 0;
                }
            } else {
                const unsigned short* p = (const unsigned short*)Wg_ + n * KIN + k0;
                fr.u2[0] = *(const uint2*)p;
                if (ks < 4 || q < 3) fr.u2[1] = *(const uint2*)(p + 4);
                else                 fr.u2[1] = make_uint2(0u, 0u);
            }
            bfr[nt][ks] = fr;
        }
    }

    // ---- zero h (h0=0) and x pads
    for (int i = tid; i < MB * HLDS_ST; i += 256) h_lds[i] = 0;
    for (int i = tid; i < 2 * MB * XLDS_ST; i += 256) x_lds[i] = 0;

    // ---- x staging: 7 threads/row, 4 elems each -> 28 elems/row
    auto stage_x = [&](int t, int buf) {
        if (tid < 224) {
            const int row = tid / 7, sub = tid % 7;
            const size_t off = (size_t)(b0 + row) * (T_STEPS * 28) + t * 28 + sub * 4;
            Pk4 pk;
            if constexpr (FP32) {
                float4 v = *(const float4*)((const float*)x_ + off);
                pk.s[0] = f2bf(v.x); pk.s[1] = f2bf(v.y);
                pk.s[2] = f2bf(v.z); pk.s[3] = f2bf(v.w);
            } else {
                pk.u2 = *(const uint2*)((const unsigned short*)x_ + off);
            }
            *(uint2*)&x_lds[buf * (MB * XLDS_ST) + row * XLDS_ST + sub * 4] = pk.u2;
        }
    };
    stage_x(0, 0);

    float c_st[2][2][4];                            // [mt][s][r] cell state, fp32
    #pragma unroll
    for (int mt = 0; mt < 2; ++mt)
        #pragma unroll
        for (int s = 0; s < 2; ++s)
            #pragma unroll
            for (int r = 0; r < 4; ++r) c_st[mt][s][r] = 0.0f;

    __syncthreads();

    #pragma unroll 1
    for (int t = 0; t < T_STEPS; ++t) {
        // prefetch next x tile into the other buffer (no reader until next step)
        if (t + 1 < T_STEPS) stage_x(t + 1, (t + 1) & 1);

        // ---- MFMA phase: gates[32 x 128] for this wave's gate
        floatx4 acc[2][NTILES];
        #pragma unroll
        for (int mt = 0; mt < 2; ++mt)
            #pragma unroll
            for (int nt = 0; nt < NTILES; ++nt) {
                const float bv = bias_r[nt];
                acc[mt][nt] = (floatx4){bv, bv, bv, bv};
            }

        #pragma unroll
        for (int mt = 0; mt < 2; ++mt) {
            Frag a[KSTEPS];
            #pragma unroll
            for (int ks = 0; ks < 4; ++ks)
                a[ks].f = *(const short8*)&h_lds[(mt * 16 + cc) * HLDS_ST + ks * 32 + q * 8];
            a[4].f = *(const short8*)&x_lds[(t & 1) * (MB * XLDS_ST) + (mt * 16 + cc) * XLDS_ST + q * 8];
            #pragma unroll
            for (int ks = 0; ks < KSTEPS; ++ks)
                #pragma unroll
                for (int nt = 0; nt < NTILES; ++nt)
                    acc[mt][nt] = __builtin_amdgcn_mfma_f32_16x16x32_bf16(
                        a[ks].f, bfr[nt][ks].f, acc[mt][nt], 0, 0, 0);
        }

        // ---- activation (wave-uniform branch) + write to gate exchange buffer
        #pragma unroll
        for (int mt = 0; mt < 2; ++mt)
            #pragma unroll
            for (int nt = 0; nt < NTILES; ++nt) {
                Pk4 pk;
                #pragma unroll
                for (int r = 0; r < 4; ++r) {
                    float v = acc[mt][nt][r];
                    v = (wave == 2) ? tanh_f(v) : sigm(v);
                    pk.s[r] = f2bf(v);
                }
                const int j  = nt * 16 + cc;        // gate output index
                const int m0 = mt * 16 + q * 4;     // C-layout rows r..r+3
                *(uint2*)&gbuf[(wave * HDIM + j) * GB_MP + m0] = pk.u2;
            }
        __syncthreads();

        // ---- elementwise phase: c,h update. Thread owns (mt,s) x 4 rows at col j.
        #pragma unroll
        for (int mt = 0; mt < 2; ++mt)
            #pragma unroll
            for (int s = 0; s < 2; ++s) {
                const int j  = wave * 32 + s * 16 + cc;
                const int m0 = mt * 16 + q * 4;
                Pk4 gf, gi, gn, go;
                gf.u2 = *(const uint2*)&gbuf[(0 * HDIM + j) * GB_MP + m0];
                gi.u2 = *(const uint2*)&gbuf[(1 * HDIM + j) * GB_MP + m0];
                gn.u2 = *(const uint2*)&gbuf[(2 * HDIM + j) * GB_MP + m0];
                go.u2 = *(const uint2*)&gbuf[(3 * HDIM + j) * GB_MP + m0];
                #pragma unroll
                for (int r = 0; r < 4; ++r) {
                    const float fv = bf2f(gf.s[r]);
                    const float iv = bf2f(gi.s[r]);
                    const float nv = bf2f(gn.s[r]);
                    const float ov = bf2f(go.s[r]);
                    const float cn = c_st[mt][s][r] * fv + iv * nv;
                    c_st[mt][s][r] = cn;
                    const float hv = ov * tanh_f(cn);
                    h_lds[(m0 + r) * HLDS_ST + j] = f2bf(hv);
                    if (t == T_STEPS - 1) {
                        const size_t oi = (size_t)(b0 + m0 + r) * HDIM + j;
                        if constexpr (FP32) ((float*)out_)[oi] = hv;
                        else                ((unsigned short*)out_)[oi] = f2bf(hv);
                    }
                }
            }
        __syncthreads();
    }
}

extern "C" void kernel_launch(void* const* d_in, const int* in_sizes, int n_in,
                              void* d_out, int out_size, void* d_ws, size_t ws_size,
                              hipStream_t stream) {
    int* flag = (int*)d_ws;
    detect_dtype<<<dim3(1), dim3(64), 0, stream>>>((const unsigned short*)d_in[1], flag);

    lstm_fused<false><<<dim3(65536 / MB), dim3(256), 0, stream>>>(
        d_in[0], d_in[1], d_in[2], d_in[3], d_in[4],
        d_in[5], d_in[6], d_in[7], d_in[8], d_out, flag);
    lstm_fused<true><<<dim3(65536 / MB), dim3(256), 0, stream>>>(
        d_in[0], d_in[1], d_in[2], d_in[3], d_in[4],
        d_in[5], d_in[6], d_in[7], d_in[8], d_out, flag);
}